// Round 5
// baseline (732.548 us; speedup 1.0000x reference)
//
#include <hip/hip_runtime.h>
#include <stdint.h>

#define Bb 8
#define Cc 256
#define Nn 2304
#define PQT 36   // proj: 64-token tiles
#define AQT 72   // attn: 32-query tiles
#define KT  72   // attn: 32-key tiles
#define L2E 1.44269504088896f

typedef unsigned short u16;
typedef __bf16 bf16;
typedef bf16 bf16x8 __attribute__((ext_vector_type(8)));
typedef u16  u16x8  __attribute__((ext_vector_type(8)));
typedef float f32x4 __attribute__((ext_vector_type(4)));
typedef int   i32x4 __attribute__((ext_vector_type(4)));

static __device__ __forceinline__ u16 f2bf(float f) {
  unsigned u = __builtin_bit_cast(unsigned, f);
  return (u16)((u + 0x7fffu + ((u >> 16) & 1u)) >> 16);
}
static __device__ __forceinline__ float bf2f(u16 h) {
  unsigned u = ((unsigned)h) << 16;
  return __builtin_bit_cast(float, u);
}
static __device__ __forceinline__ bf16x8 asbf(u16x8 v) {
  return __builtin_bit_cast(bf16x8, v);
}
static __device__ __forceinline__ f32x4 mfma16(u16x8 a, u16x8 b, f32x4 c) {
  return __builtin_amdgcn_mfma_f32_16x16x32_bf16(asbf(a), asbf(b), c, 0, 0, 0);
}
// async 16B global -> LDS DMA
static __device__ __forceinline__ void gl2lds16(const u16* g, u16* l) {
  __builtin_amdgcn_global_load_lds(
      (const __attribute__((address_space(1))) unsigned int*)g,
      (__attribute__((address_space(3))) unsigned int*)l, 16, 0, 0);
}

// ---------------------------------------------------------------------------
// Prep: Wq,Wk,Wv fp32 [C][C] -> hi/lo bf16. WHi/WLo: [3][C*C] u16.
// ---------------------------------------------------------------------------
__global__ void prep_kernel(const float* __restrict__ Wq,
                            const float* __restrict__ Wk,
                            const float* __restrict__ Wv,
                            u16* __restrict__ WHi, u16* __restrict__ WLo)
{
  const int tid = blockIdx.x * 256 + threadIdx.x;
  const int m   = tid >> 13;
  const int off = (tid & 8191) * 8;
  const float* src = (m == 0) ? Wq : (m == 1) ? Wk : Wv;
  const f32x4 a = *(const f32x4*)(src + off);
  const f32x4 c = *(const f32x4*)(src + off + 4);
  u16x8 hi, lo;
#pragma unroll
  for (int j = 0; j < 4; ++j) {
    u16 h = f2bf(a[j]); hi[j] = h; lo[j] = f2bf(a[j] - bf2f(h));
    u16 h2 = f2bf(c[j]); hi[j + 4] = h2; lo[j + 4] = f2bf(c[j] - bf2f(h2));
  }
  *(u16x8*)(WHi + (size_t)m * 65536 + off) = hi;
  *(u16x8*)(WLo + (size_t)m * 65536 + off) = lo;
}

// ---------------------------------------------------------------------------
// Projection v5: W staged through LDS per 32-c chunk (DMA coalesced, swizzled
// b128 reads) — fixes the stride-512B L2-transaction bottleneck.
// z=0 Q (hi/lo out), z=1 K (hi/lo out), z=2 V^T (bf16 out).
// grid (8, 36, 3), block 256 = 4 waves. LDS 32 KB.
// ---------------------------------------------------------------------------
__global__ __launch_bounds__(256, 3) void proj_kernel(
    const float* __restrict__ x, const float* __restrict__ y,
    const u16* __restrict__ WHi, const u16* __restrict__ WLo,
    const float* __restrict__ bq, const float* __restrict__ bk,
    const float* __restrict__ bv,
    u16* __restrict__ QHi, u16* __restrict__ QLo,
    u16* __restrict__ KHi, u16* __restrict__ KLo,
    u16* __restrict__ Vw)
{
  __shared__ u16 sWhi[256 * 32];
  __shared__ u16 sWlo[256 * 32];
  const int t    = threadIdx.x;
  const int b    = blockIdx.x;
  const int q0   = blockIdx.y * 64;
  const int z    = blockIdx.z;
  const int lane = t & 63;
  const int w    = t >> 6;
  const int quad = lane >> 4;
  const int l15  = lane & 15;

  const u16* WH = WHi + (size_t)z * 65536;
  const u16* WL = WLo + (size_t)z * 65536;

  if (z < 2) {
    // A-frags (tokens) hi/lo from global, coalesced 64B per quad
    const float* src = (z == 0) ? x : y;
    const int tok = q0 + w * 16 + l15;
    u16x8 ahi[8], alo[8];
#pragma unroll
    for (int kc = 0; kc < 8; ++kc) {
      const float* p = src + ((size_t)b * Cc + kc * 32 + quad * 8) * Nn + tok;
      float av[8];
#pragma unroll
      for (int j = 0; j < 8; ++j) av[j] = p[(size_t)j * Nn];
#pragma unroll
      for (int j = 0; j < 8; ++j) {
        const u16 h = f2bf(av[j]);
        ahi[kc][j] = h;
        alo[kc][j] = f2bf(av[j] - bf2f(h));
      }
    }
    f32x4 acc[16];
#pragma unroll
    for (int i = 0; i < 16; ++i) acc[i] = (f32x4){0.f, 0.f, 0.f, 0.f};

#pragma unroll 1
    for (int ch = 0; ch < 8; ++ch) {
      __syncthreads();
#pragma unroll
      for (int it = 0; it < 4; ++it) {
        const int id = it * 256 + t;
        const int co = id >> 2, p = id & 3, g = p ^ ((co >> 1) & 3);
        const size_t off = (size_t)co * 256 + ch * 32 + g * 8;
        gl2lds16(WH + off, sWhi + co * 32 + p * 8);
        gl2lds16(WL + off, sWlo + co * 32 + p * 8);
      }
      __syncthreads();
      const int pos = (quad ^ ((l15 >> 1) & 3)) << 3;
#pragma unroll
      for (int cb = 0; cb < 16; ++cb) {
        const int co = cb * 16 + l15;
        const u16x8 whi = *(const u16x8*)(sWhi + co * 32 + pos);
        const u16x8 wlo = *(const u16x8*)(sWlo + co * 32 + pos);
        acc[cb] = mfma16(ahi[ch], whi, acc[cb]);
        acc[cb] = mfma16(ahi[ch], wlo, acc[cb]);
        acc[cb] = mfma16(alo[ch], whi, acc[cb]);
      }
    }
    const float* bias = (z == 0) ? bq : bk;
    u16* OH = (z == 0) ? QHi : KHi;
    u16* OL = (z == 0) ? QLo : KLo;
#pragma unroll
    for (int cb = 0; cb < 16; ++cb) {
      const int co = cb * 16 + l15;
      const float bs = bias[co];
      const size_t base = ((size_t)b * Nn + q0 + w * 16 + quad * 4) * Cc + co;
#pragma unroll
      for (int r = 0; r < 4; ++r) {
        const float qv = acc[cb][r] + bs;
        const u16 h = f2bf(qv);
        OH[base + (size_t)r * Cc] = h;
        OL[base + (size_t)r * Cc] = f2bf(qv - bf2f(h));
      }
    }
  } else {
    // V^T: A = Wv (M=co, from LDS), B = y tokens (wave-partitioned)
    f32x4 acc[16];
#pragma unroll
    for (int i = 0; i < 16; ++i) acc[i] = (f32x4){0.f, 0.f, 0.f, 0.f};
    const int tok = q0 + w * 16 + l15;

#pragma unroll 1
    for (int ch = 0; ch < 8; ++ch) {
      __syncthreads();
#pragma unroll
      for (int it = 0; it < 4; ++it) {
        const int id = it * 256 + t;
        const int co = id >> 2, p = id & 3, g = p ^ ((co >> 1) & 3);
        gl2lds16(WH + (size_t)co * 256 + ch * 32 + g * 8, sWhi + co * 32 + p * 8);
      }
      __syncthreads();
      // y B-frag for this chunk
      const float* p = y + ((size_t)b * Cc + ch * 32 + quad * 8) * Nn + tok;
      u16x8 yf;
#pragma unroll
      for (int j = 0; j < 8; ++j) yf[j] = f2bf(p[(size_t)j * Nn]);
      const int pos = (quad ^ ((l15 >> 1) & 3)) << 3;
#pragma unroll
      for (int mt = 0; mt < 16; ++mt) {
        const u16x8 wf = *(const u16x8*)(sWhi + (mt * 16 + l15) * 32 + pos);
        acc[mt] = mfma16(wf, yf, acc[mt]);
      }
    }
#pragma unroll
    for (int mt = 0; mt < 16; ++mt) {
      const int crow = mt * 16 + quad * 4;
      u16* vout = Vw + ((size_t)b * Cc + crow) * Nn + q0 + w * 16 + l15;
#pragma unroll
      for (int r = 0; r < 4; ++r)
        vout[(size_t)r * Nn] = f2bf(acc[mt][r] + bv[crow + r]);
    }
  }
}

// ---------------------------------------------------------------------------
// Flash attention v5: S^T orientation (A=K, B=Q), 2 waves x 32 queries,
// c-half per wave for PV, KSPLIT=1 (no merge). grid (8, 72), block 128.
// LDS 52 KB: sKhi/sKlo [32][256], sV [256][32], sP 2x2KB. 3 blocks/CU.
// ---------------------------------------------------------------------------
__global__ __launch_bounds__(128, 2) void attn_kernel(
    const u16* __restrict__ QHi, const u16* __restrict__ QLo,
    const u16* __restrict__ KHi, const u16* __restrict__ KLo,
    const u16* __restrict__ Vw, float* __restrict__ out)
{
  __shared__ u16 sKhi[32 * 256];
  __shared__ u16 sKlo[32 * 256];
  __shared__ u16 sV[256 * 32];
  __shared__ u16 sP[2 * 1024];
  const int t     = threadIdx.x;
  const int b     = blockIdx.x;
  const int q0    = blockIdx.y * 32;
  const int lane  = t & 63;
  const int w     = t >> 6;
  const int quad  = lane >> 4;
  const int l15   = lane & 15;
  const int wbase = w * 128;                       // c-half for PV

  // Q B-frags (both query groups), hi/lo
  u16x8 qh[2][8], ql[2][8];
#pragma unroll
  for (int qg = 0; qg < 2; ++qg) {
    const size_t qrow = ((size_t)b * Nn + q0 + qg * 16 + l15) * Cc;
#pragma unroll
    for (int kc = 0; kc < 8; ++kc) {
      qh[qg][kc] = *(const u16x8*)(QHi + qrow + kc * 32 + quad * 8);
      ql[qg][kc] = *(const u16x8*)(QLo + qrow + kc * 32 + quad * 8);
    }
  }

  f32x4 o[16];   // [ct][qg] : O^T rows c = wbase+ct*16+quad*4+r, col q
#pragma unroll
  for (int i = 0; i < 16; ++i) o[i] = (f32x4){0.f, 0.f, 0.f, 0.f};
  float m_[2] = {-3e38f, -3e38f};
  float l_[2] = {0.f, 0.f};

  const u16* KhiB = KHi + (size_t)b * Nn * Cc;
  const u16* KloB = KLo + (size_t)b * Nn * Cc;
  const u16* VB   = Vw + (size_t)b * Cc * Nn;
  const int sw = (l15 & 6) | ((l15 >> 3) & 1);     // sP swizzle key
  u16* Pw = sP + w * 1024;

#pragma unroll 1
  for (int kb = 0; kb < KT; ++kb) {
    __syncthreads();
    // ---- stage K hi/lo [32][256] + V^T [256][32] via DMA (swizzled) ----
    const size_t kbase = (size_t)kb * 32;
#pragma unroll
    for (int it = 0; it < 8; ++it) {
      const int id = it * 128 + t;
      {
        const int row = id >> 5, i = id & 31, g = i ^ (row & 7);
        const size_t off = (kbase + row) * Cc + g * 8;
        gl2lds16(KhiB + off, sKhi + row * 256 + i * 8);
        gl2lds16(KloB + off, sKlo + row * 256 + i * 8);
      }
      {
        const int c = id >> 2, p = id & 3, g = p ^ ((c >> 1) & 3);
        gl2lds16(VB + (size_t)c * Nn + kbase + g * 8, sV + c * 32 + p * 8);
      }
    }
    __syncthreads();

    // ---- S^T = K Q^T : A = K rows (16 keys per mt), B = Q regs ----
    f32x4 s00 = {0.f,0.f,0.f,0.f}, s01 = s00, s10 = s00, s11 = s00;
#pragma unroll
    for (int kc = 0; kc < 8; ++kc) {
      const int ch = ((kc * 4 + quad) ^ (l15 & 7)) * 8;
      const u16x8 kh0 = *(const u16x8*)(sKhi + l15 * 256 + ch);
      const u16x8 kl0 = *(const u16x8*)(sKlo + l15 * 256 + ch);
      const u16x8 kh1 = *(const u16x8*)(sKhi + (16 + l15) * 256 + ch);
      const u16x8 kl1 = *(const u16x8*)(sKlo + (16 + l15) * 256 + ch);
      s00 = mfma16(kh0, qh[0][kc], s00);
      s01 = mfma16(kh0, qh[1][kc], s01);
      s10 = mfma16(kh1, qh[0][kc], s10);
      s11 = mfma16(kh1, qh[1][kc], s11);
      s00 = mfma16(kl0, qh[0][kc], s00);
      s01 = mfma16(kl0, qh[1][kc], s01);
      s10 = mfma16(kl1, qh[0][kc], s10);
      s11 = mfma16(kl1, qh[1][kc], s11);
      s00 = mfma16(kh0, ql[0][kc], s00);
      s01 = mfma16(kh0, ql[1][kc], s01);
      s10 = mfma16(kh1, ql[0][kc], s10);
      s11 = mfma16(kh1, ql[1][kc], s11);
    }

    // ---- online softmax per query group (keys live in regs + quads) ----
    float al[2];
#pragma unroll
    for (int qg = 0; qg < 2; ++qg) {
      f32x4 sa = qg ? s01 : s00;
      f32x4 sb = qg ? s11 : s10;
      float mx = fmaxf(fmaxf(fmaxf(sa[0], sa[1]), fmaxf(sa[2], sa[3])),
                       fmaxf(fmaxf(sb[0], sb[1]), fmaxf(sb[2], sb[3])));
      mx = fmaxf(mx, __shfl_xor(mx, 16, 64));
      mx = fmaxf(mx, __shfl_xor(mx, 32, 64));
      const float mn = fmaxf(m_[qg], mx);
      al[qg] = exp2f((m_[qg] - mn) * L2E);
      m_[qg] = mn;
      float sum = 0.f;
#pragma unroll
      for (int r = 0; r < 4; ++r) {
        sa[r] = exp2f((sa[r] - mn) * L2E);
        sb[r] = exp2f((sb[r] - mn) * L2E);
        sum += sa[r] + sb[r];
      }
      sum += __shfl_xor(sum, 16, 64);
      sum += __shfl_xor(sum, 32, 64);
      l_[qg] = l_[qg] * al[qg] + sum;
      if (qg) { s01 = sa; s11 = sb; } else { s00 = sa; s10 = sb; }
    }
    if (__any((al[0] < 1.f) | (al[1] < 1.f))) {
#pragma unroll
      for (int ct = 0; ct < 8; ++ct) {
#pragma unroll
        for (int r = 0; r < 4; ++r) {
          o[ct * 2][r]     *= al[0];
          o[ct * 2 + 1][r] *= al[1];
        }
      }
    }

    // ---- P^T: C/D -> sP (8B-unit swizzle) -> B-operand A-layout ----
    {
      const int p0 = (0 ^ sw) << 2;            // mt0: key>>2 = quad + 0
      const int p1 = (4 ^ sw) << 2;            // mt1: key>>2 = quad + 4
#pragma unroll
      for (int qg = 0; qg < 2; ++qg) {
        u16* row = Pw + (qg * 16 + l15) * 32;
        const f32x4 sa = qg ? s01 : s00;
        const f32x4 sb = qg ? s11 : s10;
#pragma unroll
        for (int r = 0; r < 4; ++r) {
          row[((quad ^ sw) << 2) + r]       = f2bf(sa[r]);
          row[(((quad + 4) ^ sw) << 2) + r] = f2bf(sb[r]);
        }
      }
    }
    __builtin_amdgcn_s_waitcnt(0xC07F);        // lgkmcnt(0)
    u16x8 pf[2];
#pragma unroll
    for (int qg = 0; qg < 2; ++qg) {
      const int E = ((2 * quad) ^ sw) & ~1;
      const u16x8 p = *(const u16x8*)(Pw + (qg * 16 + l15) * 32 + E * 4);
      const i32x4 pi = __builtin_bit_cast(i32x4, p);
      const i32x4 alt = __builtin_shufflevector(pi, pi, 2, 3, 0, 1);
      pf[qg] = __builtin_bit_cast(u16x8, (l15 & 8) ? alt : pi);
    }

    // ---- O^T += V^T P^T (c-half per wave; V A-frag shared across qg) ----
#pragma unroll
    for (int ct = 0; ct < 8; ++ct) {
      const int c = wbase + ct * 16 + l15;
      const u16x8 vf = *(const u16x8*)(sV + c * 32 + ((quad ^ ((c >> 1) & 3)) << 3));
      o[ct * 2]     = mfma16(vf, pf[0], o[ct * 2]);
      o[ct * 2 + 1] = mfma16(vf, pf[1], o[ct * 2 + 1]);
    }
  }

  // ---- epilogue: out[b][c][n] = O^T / l (direct, no merge) ----
  const float inv0 = 1.0f / l_[0];
  const float inv1 = 1.0f / l_[1];
#pragma unroll
  for (int ct = 0; ct < 8; ++ct) {
    const int cbase = wbase + ct * 16 + quad * 4;
#pragma unroll
    for (int r = 0; r < 4; ++r) {
      float* op = out + ((size_t)b * Cc + cbase + r) * Nn + q0 + l15;
      op[0]  = o[ct * 2][r] * inv0;
      op[16] = o[ct * 2 + 1][r] * inv1;
    }
  }
}

extern "C" void kernel_launch(void* const* d_in, const int* in_sizes, int n_in,
                              void* d_out, int out_size, void* d_ws, size_t ws_size,
                              hipStream_t stream) {
  const float* x  = (const float*)d_in[0];
  const float* y  = (const float*)d_in[1];
  const float* Wq = (const float*)d_in[2];
  const float* bq = (const float*)d_in[3];
  const float* Wk = (const float*)d_in[4];
  const float* bk = (const float*)d_in[5];
  const float* Wv = (const float*)d_in[6];
  const float* bv = (const float*)d_in[7];
  float* out = (float*)d_out;

  const size_t NC = (size_t)Bb * Nn * Cc;   // 4,718,592
  u16* QHi = (u16*)d_ws;
  u16* QLo = QHi + NC;
  u16* KHi = QLo + NC;
  u16* KLo = KHi + NC;
  u16* Vw  = KLo + NC;
  u16* WHi = Vw + NC;
  u16* WLo = WHi + 3 * 65536;

  hipLaunchKernelGGL(prep_kernel, dim3(96), dim3(256), 0, stream,
                     Wq, Wk, Wv, WHi, WLo);
  hipLaunchKernelGGL(proj_kernel, dim3(Bb, PQT, 3), dim3(256), 0, stream,
                     x, y, WHi, WLo, bq, bk, bv, QHi, QLo, KHi, KLo, Vw);
  hipLaunchKernelGGL(attn_kernel, dim3(Bb, AQT), dim3(128), 0, stream,
                     QHi, QLo, KHi, KLo, Vw, out);
}

// Round 6
// 323.624 us; speedup vs baseline: 2.2636x; 2.2636x over previous
//
#include <hip/hip_runtime.h>
#include <stdint.h>

#define Bb 8
#define Cc 256
#define Nn 2304
#define PQT 36   // proj: 64-token tiles
#define QTILES 36
#define KSPLIT 2
#define TPS 36   // 32-key tiles per split
#define L2E 1.44269504088896f

typedef unsigned short u16;
typedef _Float16 h16;
typedef h16  h16x8 __attribute__((ext_vector_type(8)));
typedef u16  u16x8 __attribute__((ext_vector_type(8)));
typedef float f32x4 __attribute__((ext_vector_type(4)));

static __device__ __forceinline__ u16 f2h(float f) {
  return __builtin_bit_cast(u16, (h16)f);
}
static __device__ __forceinline__ h16x8 ash(u16x8 v) {
  return __builtin_bit_cast(h16x8, v);
}
static __device__ __forceinline__ f32x4 mfma16(u16x8 a, u16x8 b, f32x4 c) {
  return __builtin_amdgcn_mfma_f32_16x16x32_f16(ash(a), ash(b), c, 0, 0, 0);
}

// DPP row_ror reductions over 16 lanes (VALU pipe)
template <int CTRL>
static __device__ __forceinline__ float dppmov(float x) {
  return __builtin_bit_cast(float,
      __builtin_amdgcn_mov_dpp(__builtin_bit_cast(int, x), CTRL, 0xF, 0xF, true));
}
static __device__ __forceinline__ float rowmax16(float x) {
  x = fmaxf(x, dppmov<0x121>(x));
  x = fmaxf(x, dppmov<0x122>(x));
  x = fmaxf(x, dppmov<0x124>(x));
  x = fmaxf(x, dppmov<0x128>(x));
  return x;
}
static __device__ __forceinline__ float rowsum16(float x) {
  x += dppmov<0x121>(x);
  x += dppmov<0x122>(x);
  x += dppmov<0x124>(x);
  x += dppmov<0x128>(x);
  return x;
}

// ---------------------------------------------------------------------------
// Prep: Wq,Wk,Wv fp32 [C][C] -> fp16 Wf [3][C*C].
// ---------------------------------------------------------------------------
__global__ void prep_kernel(const float* __restrict__ Wq,
                            const float* __restrict__ Wk,
                            const float* __restrict__ Wv,
                            u16* __restrict__ Wf)
{
  const int tid = blockIdx.x * 256 + threadIdx.x;
  const int m   = tid >> 13;
  const int off = (tid & 8191) * 8;
  const float* src = (m == 0) ? Wq : (m == 1) ? Wk : Wv;
  const f32x4 a = *(const f32x4*)(src + off);
  const f32x4 c = *(const f32x4*)(src + off + 4);
  u16x8 o;
#pragma unroll
  for (int j = 0; j < 4; ++j) { o[j] = f2h(a[j]); o[j + 4] = f2h(c[j]); }
  *(u16x8*)(Wf + (size_t)m * 65536 + off) = o;
}

// ---------------------------------------------------------------------------
// Projection v6 (all fp16, 1-term). W staged 32 full rows at a time in LDS
// (coalesced 512B row loads, XOR-swizzled b128 reads). z=0: Q [B][N][C],
// z=1: K [B][N][C], z=2: V^T [B][C][N]. grid (8,36,3), block 256.
// ---------------------------------------------------------------------------
__global__ __launch_bounds__(256, 3) void proj_kernel(
    const float* __restrict__ x, const float* __restrict__ y,
    const u16* __restrict__ Wf,
    const float* __restrict__ bq, const float* __restrict__ bk,
    const float* __restrict__ bv,
    u16* __restrict__ Qf, u16* __restrict__ Kf, u16* __restrict__ Vf)
{
  __shared__ u16 sW[32 * 256];   // 16 KB
  const int t    = threadIdx.x;
  const int b    = blockIdx.x;
  const int q0   = blockIdx.y * 64;
  const int z    = blockIdx.z;
  const int lane = t & 63;
  const int w    = t >> 6;
  const int quad = lane >> 4;
  const int l15  = lane & 15;

  const u16* WZ = Wf + (size_t)z * 65536;
  const int srow = t >> 5;        // staging: row 0..7 (+8*it later? no: id)
  const int sch  = t & 31;        // staging chunk

  // token fragments (A for z<2, B for z==2): lane l15 -> token, k=quad*8+j
  const float* src = (z == 0) ? x : y;
  const int tok = q0 + w * 16 + l15;
  u16x8 af[8];
#pragma unroll
  for (int kc = 0; kc < 8; ++kc) {
    const float* p = src + ((size_t)b * Cc + kc * 32 + quad * 8) * Nn + tok;
    float v[8];
#pragma unroll
    for (int j = 0; j < 8; ++j) v[j] = p[(size_t)j * Nn];
#pragma unroll
    for (int j = 0; j < 8; ++j) af[kc][j] = f2h(v[j]);
  }

  f32x4 acc[16];
#pragma unroll
  for (int i = 0; i < 16; ++i) acc[i] = (f32x4){0.f, 0.f, 0.f, 0.f};

#pragma unroll 1
  for (int rg = 0; rg < 8; ++rg) {   // 32 c_out rows per round
    __syncthreads();
#pragma unroll
    for (int it = 0; it < 4; ++it) {
      const int id = it * 256 + t;
      const int row = id >> 5, gch = id & 31;
      const u16x8 v = *(const u16x8*)(WZ + (size_t)(rg * 32 + row) * 256 + gch * 8);
      *(u16x8*)(sW + row * 256 + ((gch ^ (row & 7)) << 3)) = v;
    }
    __syncthreads();
    if (z < 2) {
#pragma unroll
      for (int cbl = 0; cbl < 2; ++cbl) {
        const int rl = cbl * 16 + l15;
        f32x4 a = acc[rg * 2 + cbl];
#pragma unroll
        for (int kc = 0; kc < 8; ++kc) {
          const u16x8 bf = *(const u16x8*)(sW + rl * 256 + (((kc * 4 + quad) ^ (rl & 7)) << 3));
          a = mfma16(af[kc], bf, a);
        }
        acc[rg * 2 + cbl] = a;
      }
    } else {
#pragma unroll
      for (int mt = 0; mt < 2; ++mt) {
        const int rl = mt * 16 + l15;
        f32x4 a = acc[rg * 2 + mt];
#pragma unroll
        for (int kc = 0; kc < 8; ++kc) {
          const u16x8 wfr = *(const u16x8*)(sW + rl * 256 + (((kc * 4 + quad) ^ (rl & 7)) << 3));
          a = mfma16(wfr, af[kc], a);
        }
        acc[rg * 2 + mt] = a;
      }
    }
  }

  // epilogues
  if (z < 2) {
    const float* bias = (z == 0) ? bq : bk;
    u16* O = (z == 0) ? Qf : Kf;
#pragma unroll
    for (int cb = 0; cb < 16; ++cb) {
      const int co = cb * 16 + l15;
      const float bs = bias[co];
      const size_t base = ((size_t)b * Nn + q0 + w * 16 + quad * 4) * Cc + co;
#pragma unroll
      for (int r = 0; r < 4; ++r)
        O[base + (size_t)r * Cc] = f2h(acc[cb][r] + bs);
    }
  } else {
#pragma unroll
    for (int cb = 0; cb < 16; ++cb) {
      const int crow = cb * 16 + quad * 4;
#pragma unroll
      for (int r = 0; r < 4; ++r)
        Vf[((size_t)b * Cc + crow + r) * Nn + q0 + w * 16 + l15] =
            f2h(acc[cb][r] + bv[crow + r]);
    }
  }
}

// ---------------------------------------------------------------------------
// Flash attention v6 (all fp16, 1-term). grid (8,36,2), block 256 = 4 waves
// x 16 queries. 32-key tiles, register-prefetch pipeline (coalesced loads).
// LDS 36 KB: sK [32][256], sV [256 c][32 keys], sP 4x1KB. 3 blocks/CU.
// ---------------------------------------------------------------------------
__global__ __launch_bounds__(256, 3) void attn_kernel(
    const u16* __restrict__ Qf, const u16* __restrict__ Kf,
    const u16* __restrict__ Vf, float* __restrict__ Opart,
    float* __restrict__ Ml)
{
  __shared__ u16 sK[32 * 256];   // 16 KB
  __shared__ u16 sV[256 * 32];   // 16 KB
  __shared__ u16 sP[4 * 512];    //  4 KB
  const int t    = threadIdx.x;
  const int b    = blockIdx.x;
  const int q0   = blockIdx.y * 64;
  const int sp   = blockIdx.z;
  const int lane = t & 63;
  const int w    = t >> 6;
  const int quad = lane >> 4;
  const int l15  = lane & 15;

  // Q A-frags
  u16x8 qf[8];
  {
    const size_t qrow = ((size_t)b * Nn + q0 + w * 16 + l15) * Cc;
#pragma unroll
    for (int kc = 0; kc < 8; ++kc)
      qf[kc] = *(const u16x8*)(Qf + qrow + kc * 32 + quad * 8);
  }

  f32x4 o[16];
#pragma unroll
  for (int i = 0; i < 16; ++i) o[i] = (f32x4){0.f, 0.f, 0.f, 0.f};
  float mrow[4] = {-3e38f, -3e38f, -3e38f, -3e38f};
  float lrow[4] = {0.f, 0.f, 0.f, 0.f};

  const u16* Kb = Kf + (size_t)b * Nn * Cc;
  const u16* Vb = Vf + (size_t)b * Cc * Nn;
  const int gl = (l15 & 3) ^ ((l15 >> 2) & 3);

  // staging geometry (per-thread constants)
  const int krow = t >> 5;               // K: row 0..7 (+8*it)
  const int kch  = t & 31;               // K: global chunk (linear, coalesced)
  const int vc   = t >> 2;               // V: c row 0..63 (+64*it)
  const int vp   = t & 3;                // V: chunk

  u16x8 pk[4], pv[4];
  {
    const size_t kg0 = (size_t)sp * TPS * 32;
#pragma unroll
    for (int it = 0; it < 4; ++it) {
      pk[it] = *(const u16x8*)(Kb + (kg0 + krow + it * 8) * Cc + kch * 8);
      pv[it] = *(const u16x8*)(Vb + (size_t)(it * 64 + vc) * Nn + kg0 + vp * 8);
    }
  }

#pragma unroll 1
  for (int kb = 0; kb < TPS; ++kb) {
    __syncthreads();   // prev tile's LDS reads done
    // ---- regs -> LDS (swizzled on the LDS side) ----
#pragma unroll
    for (int it = 0; it < 4; ++it) {
      const int row = krow + it * 8;
      *(u16x8*)(sK + row * 256 + ((kch ^ (row & 7)) << 3)) = pk[it];
      const int c = it * 64 + vc;
      *(u16x8*)(sV + c * 32 + ((vp ^ ((c >> 1) & 3)) << 3)) = pv[it];
    }
    __syncthreads();
    // ---- prefetch next tile (drains at next tile's ds_write) ----
    if (kb + 1 < TPS) {
      const size_t kg0 = ((size_t)sp * TPS + kb + 1) * 32;
#pragma unroll
      for (int it = 0; it < 4; ++it) {
        pk[it] = *(const u16x8*)(Kb + (kg0 + krow + it * 8) * Cc + kch * 8);
        pv[it] = *(const u16x8*)(Vb + (size_t)(it * 64 + vc) * Nn + kg0 + vp * 8);
      }
    }

    // ---- S = Q K^T (two 16-key blocks) ----
    f32x4 s0 = {0.f, 0.f, 0.f, 0.f}, s1 = s0;
#pragma unroll
    for (int kc = 0; kc < 8; ++kc) {
      const int ch = ((kc * 4 + quad) ^ (l15 & 7)) << 3;
      const u16x8 k0 = *(const u16x8*)(sK + l15 * 256 + ch);
      const u16x8 k1 = *(const u16x8*)(sK + (16 + l15) * 256 + ch);
      s0 = mfma16(qf[kc], k0, s0);
      s1 = mfma16(qf[kc], k1, s1);
    }

    // ---- online softmax (4 independent DPP chains) ----
    float m0[4], al[4], sums[4];
#pragma unroll
    for (int r = 0; r < 4; ++r) m0[r] = fmaxf(s0[r], s1[r]);
#pragma unroll
    for (int r = 0; r < 4; ++r) m0[r] = rowmax16(m0[r]);
#pragma unroll
    for (int r = 0; r < 4; ++r) {
      const float mn = fmaxf(mrow[r], m0[r]);
      al[r] = exp2f((mrow[r] - mn) * L2E);
      mrow[r] = mn;
      const float p0 = exp2f((s0[r] - mn) * L2E);
      const float p1 = exp2f((s1[r] - mn) * L2E);
      s0[r] = p0; s1[r] = p1;
      sums[r] = p0 + p1;
    }
#pragma unroll
    for (int r = 0; r < 4; ++r) sums[r] = rowsum16(sums[r]);
#pragma unroll
    for (int r = 0; r < 4; ++r) lrow[r] = lrow[r] * al[r] + sums[r];

    if (__any((al[0] < 1.f) | (al[1] < 1.f) | (al[2] < 1.f) | (al[3] < 1.f))) {
#pragma unroll
      for (int i = 0; i < 16; ++i) {
#pragma unroll
        for (int r = 0; r < 4; ++r) o[i][r] *= al[r];
      }
    }

    // ---- P: C/D -> sP (wave-local) -> A layout ----
    {
      u16* P = sP + w * 512;
      const int kch0 = l15 >> 3;
#pragma unroll
      for (int r = 0; r < 4; ++r) {
        const int row = quad * 4 + r;
        const int gx = r ^ quad;
        P[row * 32 + ((kch0 ^ gx) << 3) + (l15 & 7)] = f2h(s0[r]);
        P[row * 32 + (((2 + kch0) ^ gx) << 3) + (l15 & 7)] = f2h(s1[r]);
      }
    }
    __builtin_amdgcn_s_waitcnt(0xC07F);  // lgkmcnt(0)
    const u16x8 pf = *(const u16x8*)(sP + w * 512 + l15 * 32 + ((quad ^ gl) << 3));

    // ---- O += P V (16 independent accumulators) ----
#pragma unroll
    for (int cb2 = 0; cb2 < 16; ++cb2) {
      const int c = cb2 * 16 + l15;
      const u16x8 vf = *(const u16x8*)(sV + c * 32 + ((quad ^ ((c >> 1) & 3)) << 3));
      o[cb2] = mfma16(pf, vf, o[cb2]);
    }
  }

  // ---- epilogue: unnormalized partials ----
  float* Ob = Opart + ((size_t)sp * Bb + b) * (size_t)Cc * Nn;
#pragma unroll
  for (int cb2 = 0; cb2 < 16; ++cb2) {
    const int c = cb2 * 16 + l15;
    *(f32x4*)(Ob + (size_t)c * Nn + q0 + w * 16 + quad * 4) = o[cb2];
  }
  if (l15 == 0) {
    float* mlb = Ml + ((size_t)sp * Bb + b) * (size_t)Nn * 2;
#pragma unroll
    for (int r = 0; r < 4; ++r) {
      const int n = q0 + w * 16 + quad * 4 + r;
      mlb[n * 2]     = mrow[r];
      mlb[n * 2 + 1] = lrow[r];
    }
  }
}

// ---------------------------------------------------------------------------
// Merge the 2 K-split partials.
// ---------------------------------------------------------------------------
__global__ void merge_kernel(const float* __restrict__ Opart,
                             const float* __restrict__ Ml,
                             float* __restrict__ out)
{
  const int idx = blockIdx.x * 256 + threadIdx.x;
  const int n4 = idx % 576;
  const int bc = idx / 576;
  const int b  = bc >> 8;
  const size_t o0off = (size_t)bc * Nn + n4 * 4;
  const f32x4 o0 = *(const f32x4*)(Opart + o0off);
  const f32x4 o1 = *(const f32x4*)(Opart + o0off + (size_t)Bb * Cc * Nn);
  const float* ml0 = Ml + (size_t)b * Nn * 2 + n4 * 8;
  const float* ml1 = ml0 + (size_t)Bb * Nn * 2;
  const f32x4 a0 = *(const f32x4*)ml0;
  const f32x4 a1 = *(const f32x4*)(ml0 + 4);
  const f32x4 c0 = *(const f32x4*)ml1;
  const f32x4 c1 = *(const f32x4*)(ml1 + 4);
  f32x4 r;
#pragma unroll
  for (int j = 0; j < 4; ++j) {
    const float m0 = (j < 2) ? a0[j * 2] : a1[(j - 2) * 2];
    const float l0 = (j < 2) ? a0[j * 2 + 1] : a1[(j - 2) * 2 + 1];
    const float m1 = (j < 2) ? c0[j * 2] : c1[(j - 2) * 2];
    const float l1 = (j < 2) ? c0[j * 2 + 1] : c1[(j - 2) * 2 + 1];
    const float m = fmaxf(m0, m1);
    const float w0 = exp2f((m0 - m) * L2E);
    const float w1 = exp2f((m1 - m) * L2E);
    r[j] = (o0[j] * w0 + o1[j] * w1) / (l0 * w0 + l1 * w1);
  }
  *(f32x4*)(out + o0off) = r;
}

extern "C" void kernel_launch(void* const* d_in, const int* in_sizes, int n_in,
                              void* d_out, int out_size, void* d_ws, size_t ws_size,
                              hipStream_t stream) {
  const float* x  = (const float*)d_in[0];
  const float* y  = (const float*)d_in[1];
  const float* Wq = (const float*)d_in[2];
  const float* bq = (const float*)d_in[3];
  const float* Wk = (const float*)d_in[4];
  const float* bk = (const float*)d_in[5];
  const float* Wv = (const float*)d_in[6];
  const float* bv = (const float*)d_in[7];
  float* out = (float*)d_out;

  const size_t NC = (size_t)Bb * Nn * Cc;   // 4,718,592
  u16* Qf = (u16*)d_ws;
  u16* Kf = Qf + NC;
  u16* Vf = Kf + NC;
  u16* Wf = Vf + NC;
  float* Opart = (float*)(Wf + 3 * 65536);
  float* Ml    = Opart + (size_t)KSPLIT * NC;

  hipLaunchKernelGGL(prep_kernel, dim3(96), dim3(256), 0, stream,
                     Wq, Wk, Wv, Wf);
  hipLaunchKernelGGL(proj_kernel, dim3(Bb, PQT, 3), dim3(256), 0, stream,
                     x, y, Wf, bq, bk, bv, Qf, Kf, Vf);
  hipLaunchKernelGGL(attn_kernel, dim3(Bb, QTILES, KSPLIT), dim3(256), 0, stream,
                     Qf, Kf, Vf, Opart, Ml);
  hipLaunchKernelGGL(merge_kernel, dim3(4608), dim3(256), 0, stream,
                     Opart, Ml, out);
}